// Round 6
// baseline (457.034 us; speedup 1.0000x reference)
//
#include <hip/hip_runtime.h>

#define BB 16
#define DD 512
#define TT 4096
#define KK 1024
#define NN (BB*TT)              // 65536 rows
#define ROWS 64                 // t-rows per block
#define BLOCKT 1024             // 16 waves
#define NWAVES 16
#define MARGIN 2e-3f            // proven coverage margin (r4/r5 passed with it)
#define CM 6                    // candidate slots per row
#define PMAX 512                // max replay pairs per block
#define XLD 65                  // padded leading dim for f32 x tile

typedef __attribute__((ext_vector_type(8))) short short8v;   // 8 bf16
typedef __attribute__((ext_vector_type(4))) float f32x4;

// ---- bf16 helper (RNE) ----
__device__ __forceinline__ unsigned short f2bf(float f) {
    unsigned int u = __float_as_uint(f);
    unsigned int r = (u + 0x7fffu + ((u >> 16) & 1u)) >> 16;
    return (unsigned short)r;
}

// ---- numpy pairwise-sum replication (fp32, squares) — verified passing ----
__device__ __forceinline__ float pw128_sq_strided(const float* a, int stride) {
    float V[16];
    #pragma unroll
    for (int l = 0; l < 16; ++l) {
        float q[8];
        #pragma unroll
        for (int k = 0; k < 8; ++k) {
            float e = a[(l + 16 * k) * stride];
            q[k] = __fmul_rn(e, e);
        }
        V[l] = __fadd_rn(__fadd_rn(__fadd_rn(q[0], q[1]), __fadd_rn(q[2], q[3])),
                         __fadd_rn(__fadd_rn(q[4], q[5]), __fadd_rn(q[6], q[7])));
    }
    float u[8];
    #pragma unroll
    for (int l = 0; l < 8; ++l) u[l] = __fadd_rn(V[l], V[l + 8]);
    float v[4];
    #pragma unroll
    for (int l = 0; l < 4; ++l) v[l] = __fadd_rn(u[l], u[l + 4]);
    return __fadd_rn(__fadd_rn(v[0], v[2]), __fadd_rn(v[1], v[3]));
}
__device__ __forceinline__ float pw512_sq_strided(const float* a, int stride) {
    float p0 = pw128_sq_strided(a, stride);
    float p1 = pw128_sq_strided(a + 128 * stride, stride);
    float p2 = pw128_sq_strided(a + 256 * stride, stride);
    float p3 = pw128_sq_strided(a + 384 * stride, stride);
    return __fadd_rn(__fadd_rn(p0, p1), __fadd_rn(p2, p3));
}

// ---------------- exact ||e||^2 per code row ----------------
__global__ void enorms_exact(const float* __restrict__ E, float* __restrict__ se) {
    int i = blockIdx.x * blockDim.x + threadIdx.x;
    if (i < KK) se[i] = pw512_sq_strided(E + (long)i * DD, 1);
}

// ---------------- pack E (hi bf16) into MFMA B-fragment layout ----------
__global__ void pack_e(const float* __restrict__ E, unsigned short* __restrict__ Bph) {
    int i = blockIdx.x * blockDim.x + threadIdx.x;   // 0 .. KK*DD-1
    if (i >= KK * DD) return;
    int c = i >> 9, k = i & 511;
    int lane = (c & 15) + ((k >> 3) & 3) * 16;
    int hw = (((c >> 4) * 16 + (k >> 5)) * 64 + lane) * 8 + (k & 7);
    Bph[hw] = f2bf(E[i]);
}

// =============== k1: MFMA filter -> per-row candidate lists ===============
__global__ __launch_bounds__(BLOCKT)
void vq_filter(const float* __restrict__ x,
               const unsigned short* __restrict__ Bph,
               const float* __restrict__ se,
               uint4* __restrict__ cands) {
    __shared__ __align__(16) unsigned short Ahi[ROWS * DD];  // 64 KB, fragment layout
    __shared__ float wrowmin[NWAVES * ROWS];
    __shared__ float gthr[ROWS];
    __shared__ int   rcnt[ROWS];
    __shared__ unsigned short rc[ROWS][CM];

    const int tid  = threadIdx.x;
    const int w    = tid >> 6;
    const int lane = tid & 63;
    const int blk  = blockIdx.x;
    const int b    = blk >> 6;
    const int t0   = (blk & 63) * ROWS;
    const long nbase = (long)b * TT + t0;
    const float* xb = x + (long)b * DD * TT + t0;

    if (tid < ROWS) rcnt[tid] = 0;

    // ---- stage x tile -> bf16-hi A fragments (coalesced loads, b128 writes) ----
    {
        const float* xbl = xb + lane;
        #pragma unroll
        for (int it = 0; it < 4; ++it) {
            int d0 = (it * NWAVES + w) * 8;
            float v[8];
            #pragma unroll
            for (int jj = 0; jj < 8; ++jj)
                v[jj] = xbl[(long)(d0 + jj) * TT];
            union { short8v s; unsigned short h[8]; } hv;
            #pragma unroll
            for (int jj = 0; jj < 8; ++jj) hv.h[jj] = f2bf(v[jj]);
            int kk = d0 >> 5, lg = (d0 >> 3) & 3;
            int m = lane >> 4, lp = (lane & 15) + lg * 16;
            *(short8v*)(Ahi + (size_t)((m * 16 + kk) * 64 + lp) * 8) = hv.s;
        }
    }
    __syncthreads();

    // ---- GEMM: wave owns 64 codes (4 n-tiles), all 4 m-tiles, K=512 ----
    f32x4 acc[4][4];
    #pragma unroll
    for (int m = 0; m < 4; ++m)
        #pragma unroll
        for (int n = 0; n < 4; ++n)
            acc[m][n] = (f32x4){0.f, 0.f, 0.f, 0.f};

    const short8v* Bhv = (const short8v*)Bph;
    for (int kk = 0; kk < 16; ++kk) {
        short8v bh[4];
        #pragma unroll
        for (int n = 0; n < 4; ++n)
            bh[n] = Bhv[((w * 4 + n) * 16 + kk) * 64 + lane];
        short8v ah[4];
        #pragma unroll
        for (int m = 0; m < 4; ++m)
            ah[m] = *(const short8v*)&Ahi[((size_t)((m * 16 + kk) * 64 + lane)) * 8];
        #pragma unroll
        for (int n = 0; n < 4; ++n)
            #pragma unroll
            for (int m = 0; m < 4; ++m)
                acc[m][n] = __builtin_amdgcn_mfma_f32_16x16x32_bf16(ah[m], bh[n], acc[m][n], 0, 0, 0);
    }

    // ---- per-row wave-min (C/D: col=lane&15, row=(lane>>4)*4+reg) ----
    float sef[4];
    #pragma unroll
    for (int n = 0; n < 4; ++n) sef[n] = se[w * 64 + n * 16 + (lane & 15)];

    #pragma unroll
    for (int m = 0; m < 4; ++m) {
        #pragma unroll
        for (int r4 = 0; r4 < 4; ++r4) {
            float mn = 1e30f;
            #pragma unroll
            for (int n = 0; n < 4; ++n)
                mn = fminf(mn, fmaf(-2.f, acc[m][n][r4], sef[n]));
            #pragma unroll
            for (int off = 1; off < 16; off <<= 1)
                mn = fminf(mn, __shfl_xor(mn, off, 64));
            if ((lane & 15) == 0)
                wrowmin[w * ROWS + m * 16 + (lane >> 4) * 4 + r4] = mn;
        }
    }
    __syncthreads();

    if (tid < ROWS) {
        float g = 1e30f;
        #pragma unroll
        for (int ww = 0; ww < NWAVES; ++ww)
            g = fminf(g, wrowmin[ww * ROWS + tid]);
        gthr[tid] = g + MARGIN;
    }
    __syncthreads();

    // ---- push candidates within margin into per-row slots ----
    #pragma unroll
    for (int m = 0; m < 4; ++m) {
        #pragma unroll
        for (int r4 = 0; r4 < 4; ++r4) {
            int row = m * 16 + (lane >> 4) * 4 + r4;
            float th = gthr[row];
            #pragma unroll
            for (int n = 0; n < 4; ++n) {
                float sc = fmaf(-2.f, acc[m][n][r4], sef[n]);
                if (sc <= th) {
                    int pos = atomicAdd(&rcnt[row], 1);
                    if (pos < CM)
                        rc[row][pos] = (unsigned short)(w * 64 + n * 16 + (lane & 15));
                }
            }
        }
    }
    __syncthreads();

    if (tid < ROWS) {
        uint4 cw;
        cw.x = (unsigned int)rcnt[tid];
        cw.y = (unsigned int)rc[tid][0] | ((unsigned int)rc[tid][1] << 16);
        cw.z = (unsigned int)rc[tid][2] | ((unsigned int)rc[tid][3] << 16);
        cw.w = (unsigned int)rc[tid][4] | ((unsigned int)rc[tid][5] << 16);
        cands[nbase + tid] = cw;
    }
}

// =============== k2: exact replay + argmin + gather/loss/st ===============
__global__ __launch_bounds__(BLOCKT)
void vq_out(const float* __restrict__ x, const float* __restrict__ E,
            const float* __restrict__ se, const uint4* __restrict__ cands,
            double* __restrict__ loss_acc, float* __restrict__ out) {
    __shared__ __align__(16) float xsf[DD * XLD];   // 133 KB
    __shared__ float Pp[4 * ROWS];
    __shared__ int   prow[PMAX];
    __shared__ int   pcand[PMAX];
    __shared__ float pdist[PMAX];
    __shared__ int   pcnt;
    __shared__ int   fidx[ROWS];
    __shared__ int   oflag[ROWS];
    __shared__ float owv[NWAVES];
    __shared__ int   owi[NWAVES];

    const int tid  = threadIdx.x;
    const int w    = tid >> 6;
    const int lane = tid & 63;
    const int blk  = blockIdx.x;
    const int b    = blk >> 6;
    const int t0   = (blk & 63) * ROWS;
    const long nbase = (long)b * TT + t0;
    const float* xb = x + (long)b * DD * TT + t0;

    if (tid == 0) pcnt = 0;

    // ---- stage f32 x tile [d][r] ----
    #pragma unroll
    for (int it = 0; it < 8; ++it) {
        int flat = it * BLOCKT + tid;
        int d  = flat >> 4;
        int r4 = (flat & 15) * 4;
        float4 v = *reinterpret_cast<const float4*>(xb + (long)d * TT + r4);
        *reinterpret_cast<float4*>(&xsf[d * XLD + r4]) = v;
    }
    __syncthreads();

    // ---- pw partials (tid<256) || decode candidate lists (tid 256..319) ----
    if (tid < 4 * ROWS) {
        int r = tid & 63, k = tid >> 6;
        Pp[k * ROWS + r] = pw128_sq_strided(xsf + r + (k * 128) * XLD, XLD);
    } else if (tid < 4 * ROWS + ROWS) {
        int r = tid - 4 * ROWS;
        uint4 cw = cands[nbase + r];
        int cnt = (int)cw.x;
        oflag[r] = 0;
        if (cnt == 1) {
            fidx[r] = (int)(cw.y & 0xffffu);
        } else if (cnt >= 2 && cnt <= CM) {
            fidx[r] = -1;
            int cs[CM] = {(int)(cw.y & 0xffffu), (int)(cw.y >> 16),
                          (int)(cw.z & 0xffffu), (int)(cw.z >> 16),
                          (int)(cw.w & 0xffffu), (int)(cw.w >> 16)};
            int base = atomicAdd(&pcnt, cnt);
            for (int i = 0; i < cnt; ++i) {
                prow[base + i]  = r;
                pcand[base + i] = cs[i];
            }
        } else {                 // cnt==0 (impossible) or overflow: full replay
            fidx[r] = -1;
            oflag[r] = 1;
        }
    }
    __syncthreads();

    // ---- exact fp32 replay per candidate pair (numpy semantics) ----
    const int npairs = (pcnt < PMAX) ? pcnt : PMAX;
    {
        int p = lane * NWAVES + w;
        if (p < npairs) {
            int r = prow[p], c = pcand[p];
            float sx = __fadd_rn(__fadd_rn(Pp[0 * ROWS + r], Pp[1 * ROWS + r]),
                                 __fadd_rn(Pp[2 * ROWS + r], Pp[3 * ROWS + r]));
            const float* Ep = E + (long)c * DD;
            float g = 0.f;
            #pragma unroll 8
            for (int j = 0; j < DD; ++j)
                g = __fmaf_rn(xsf[j * XLD + r], Ep[j], g);
            float t1 = __fadd_rn(sx, se[c]);
            pdist[p] = __fsub_rn(t1, __fmul_rn(2.f, g));
        }
    }
    __syncthreads();

    // ---- per-row argmin over pairs (first-occurrence tie-break) ----
    if (tid < ROWS && fidx[tid] < 0 && !oflag[tid]) {
        float bd = 1e30f; int bi = KK;
        for (int p = 0; p < npairs; ++p) {
            if (prow[p] != tid) continue;
            float d = pdist[p]; int c = pcand[p];
            if (d < bd || (d == bd && c < bi)) { bd = d; bi = c; }
        }
        fidx[tid] = bi;
    }
    __syncthreads();

    // ---- overflow fallback: full exact replay, one code per thread ----
    for (int r = 0; r < ROWS; ++r) {
        if (!oflag[r]) continue;                       // uniform branch (LDS)
        float sx = __fadd_rn(__fadd_rn(Pp[0 * ROWS + r], Pp[1 * ROWS + r]),
                             __fadd_rn(Pp[2 * ROWS + r], Pp[3 * ROWS + r]));
        int c = tid;                                   // KK == BLOCKT
        const float* Ep = E + (long)c * DD;
        float g = 0.f;
        #pragma unroll 8
        for (int j = 0; j < DD; ++j)
            g = __fmaf_rn(xsf[j * XLD + r], Ep[j], g);
        float bd = __fsub_rn(__fadd_rn(sx, se[c]), __fmul_rn(2.f, g));
        int bi = c;
        #pragma unroll
        for (int off = 32; off; off >>= 1) {
            float tv = __shfl_down(bd, off, 64);
            int   ti = __shfl_down(bi, off, 64);
            if (tv < bd || (tv == bd && ti < bi)) { bd = tv; bi = ti; }
        }
        if (lane == 0) { owv[w] = bd; owi[w] = bi; }
        __syncthreads();
        if (tid == 0) {
            float BD = 1e30f; int BI = KK;
            for (int ww = 0; ww < NWAVES; ++ww) {
                if (owv[ww] < BD || (owv[ww] == BD && owi[ww] < BI)) { BD = owv[ww]; BI = owi[ww]; }
            }
            fidx[r] = BI;
        }
        __syncthreads();
    }

    if (tid < ROWS)
        out[(size_t)NN * DD + 1 + nbase + tid] = (float)fidx[tid];
    __syncthreads();

    // ---- gather rows, quantized_st = fl(x + fl(q-x)), fp64 loss ----
    double lacc = 0.0;
    #pragma unroll
    for (int it = 0; it < 8; ++it) {
        int flat = it * BLOCKT + tid;
        int r = flat >> 7;
        int j = (flat & 127) * 4;
        int idx = fidx[r];
        float4 ev = *reinterpret_cast<const float4*>(E + (long)idx * DD + j);
        float xv0 = xsf[(j + 0) * XLD + r];
        float xv1 = xsf[(j + 1) * XLD + r];
        float xv2 = xsf[(j + 2) * XLD + r];
        float xv3 = xsf[(j + 3) * XLD + r];
        float d0 = __fsub_rn(ev.x, xv0);
        float d1 = __fsub_rn(ev.y, xv1);
        float d2 = __fsub_rn(ev.z, xv2);
        float d3 = __fsub_rn(ev.w, xv3);
        float4 st;
        st.x = __fadd_rn(xv0, d0);
        st.y = __fadd_rn(xv1, d1);
        st.z = __fadd_rn(xv2, d2);
        st.w = __fadd_rn(xv3, d3);
        *reinterpret_cast<float4*>(out + (size_t)(nbase + r) * DD + j) = st;
        lacc += (double)d0 * d0 + (double)d1 * d1 + (double)d2 * d2 + (double)d3 * d3;
    }
    #pragma unroll
    for (int off = 32; off; off >>= 1) lacc += __shfl_down(lacc, off, 64);
    if (lane == 0) atomicAdd(loss_acc, lacc);
}

// ---------------- loss finalize ----------------
__global__ void finalize_kernel(const double* __restrict__ loss_acc, float* __restrict__ out) {
    if (threadIdx.x == 0 && blockIdx.x == 0) {
        out[(size_t)NN * DD] = (float)(1.25 * (*loss_acc) / ((double)NN * DD));
    }
}

extern "C" void kernel_launch(void* const* d_in, const int* in_sizes, int n_in,
                              void* d_out, int out_size, void* d_ws, size_t ws_size,
                              hipStream_t stream) {
    const float* x = (const float*)d_in[0];
    const float* E = (const float*)d_in[1];
    float* out = (float*)d_out;
    double* loss_acc = (double*)d_ws;                                   // 8 B
    float* se = (float*)((char*)d_ws + 64);                             // 4 KB
    unsigned short* Bph = (unsigned short*)((char*)d_ws + 8192);        // 1 MB
    uint4* cands = (uint4*)((char*)d_ws + 8192 + 1048576);              // 1 MB

    hipMemsetAsync(d_ws, 0, 64, stream);
    enorms_exact<<<4, 256, 0, stream>>>(E, se);
    pack_e<<<(KK * DD) / 256, 256, 0, stream>>>(E, Bph);
    vq_filter<<<NN / ROWS, BLOCKT, 0, stream>>>(x, Bph, se, cands);
    vq_out<<<NN / ROWS, BLOCKT, 0, stream>>>(x, E, se, cands, loss_acc, out);
    finalize_kernel<<<1, 64, 0, stream>>>(loss_acc, out);
}

// Round 7
// 392.614 us; speedup vs baseline: 1.1641x; 1.1641x over previous
//
#include <hip/hip_runtime.h>

#define BB 16
#define DD 512
#define TT 4096
#define KK 1024
#define NN (BB*TT)              // 65536 rows
#define ROWS 64                 // k1: t-rows per block
#define BLOCKT 1024             // k1: 16 waves
#define NWAVES 16
#define MARGIN 1e-3f            // candidate margin (req <=8e-4, 25% slack)
#define CM 7                    // candidate slots per row (packed in uint4)
// k2 geometry
#define ROWS2 16
#define BT2 256
#define XLD2 17
#define PM2 128

typedef __attribute__((ext_vector_type(8))) short short8v;   // 8 bf16
typedef __attribute__((ext_vector_type(4))) float f32x4;

// ---- bf16 helper (RNE) ----
__device__ __forceinline__ unsigned short f2bf(float f) {
    unsigned int u = __float_as_uint(f);
    unsigned int r = (u + 0x7fffu + ((u >> 16) & 1u)) >> 16;
    return (unsigned short)r;
}

// ---- numpy pairwise-sum replication (fp32, squares) — verified passing ----
__device__ __forceinline__ float pw128_sq_strided(const float* a, int stride) {
    float V[16];
    #pragma unroll
    for (int l = 0; l < 16; ++l) {
        float q[8];
        #pragma unroll
        for (int k = 0; k < 8; ++k) {
            float e = a[(l + 16 * k) * stride];
            q[k] = __fmul_rn(e, e);
        }
        V[l] = __fadd_rn(__fadd_rn(__fadd_rn(q[0], q[1]), __fadd_rn(q[2], q[3])),
                         __fadd_rn(__fadd_rn(q[4], q[5]), __fadd_rn(q[6], q[7])));
    }
    float u[8];
    #pragma unroll
    for (int l = 0; l < 8; ++l) u[l] = __fadd_rn(V[l], V[l + 8]);
    float v[4];
    #pragma unroll
    for (int l = 0; l < 4; ++l) v[l] = __fadd_rn(u[l], u[l + 4]);
    return __fadd_rn(__fadd_rn(v[0], v[2]), __fadd_rn(v[1], v[3]));
}
__device__ __forceinline__ float pw512_sq_strided(const float* a, int stride) {
    float p0 = pw128_sq_strided(a, stride);
    float p1 = pw128_sq_strided(a + 128 * stride, stride);
    float p2 = pw128_sq_strided(a + 256 * stride, stride);
    float p3 = pw128_sq_strided(a + 384 * stride, stride);
    return __fadd_rn(__fadd_rn(p0, p1), __fadd_rn(p2, p3));
}

// ---------------- exact ||e||^2 per code row ----------------
__global__ void enorms_exact(const float* __restrict__ E, float* __restrict__ se) {
    int i = blockIdx.x * blockDim.x + threadIdx.x;
    if (i < KK) se[i] = pw512_sq_strided(E + (long)i * DD, 1);
}

// ---------------- pack E (hi bf16) into MFMA B-fragment layout (u32 pairs) --
__global__ void pack_e(const float* __restrict__ E, unsigned short* __restrict__ Bph) {
    int i = blockIdx.x * blockDim.x + threadIdx.x;   // 0 .. KK*DD/2-1
    if (i >= KK * DD / 2) return;
    int c = i >> 8;
    int k = (i & 255) * 2;                           // even k; k,k+1 share 8-group
    float2 v = *reinterpret_cast<const float2*>(E + ((long)c << 9) + k);
    int lane = (c & 15) + ((k >> 3) & 3) * 16;
    int hw = (((c >> 4) * 16 + (k >> 5)) * 64 + lane) * 8 + (k & 7);
    unsigned int pk = (unsigned int)f2bf(v.x) | ((unsigned int)f2bf(v.y) << 16);
    *reinterpret_cast<unsigned int*>(Bph + hw) = pk;
}

// =============== k1: MFMA filter -> per-row candidate lists ===============
__global__ __launch_bounds__(BLOCKT)
void vq_filter(const float* __restrict__ x,
               const unsigned short* __restrict__ Bph,
               const float* __restrict__ se,
               uint4* __restrict__ cands) {
    __shared__ __align__(16) unsigned short Ahi[ROWS * DD];  // 64 KB, fragment layout
    __shared__ float wrowmin[NWAVES * ROWS];
    __shared__ float gthr[ROWS];
    __shared__ int   rcnt[ROWS];
    __shared__ unsigned short rc[ROWS][CM];

    const int tid  = threadIdx.x;
    const int w    = tid >> 6;
    const int lane = tid & 63;
    const int blk  = blockIdx.x;
    const int b    = blk >> 6;
    const int t0   = (blk & 63) * ROWS;
    const long nbase = (long)b * TT + t0;
    const float* xb = x + (long)b * DD * TT + t0;

    if (tid < ROWS) {
        rcnt[tid] = 0;
        #pragma unroll
        for (int i = 0; i < CM; ++i) rc[tid][i] = 0;
    }

    // ---- stage x tile -> bf16-hi A fragments (coalesced loads, b128 writes) ----
    {
        const float* xbl = xb + lane;
        #pragma unroll
        for (int it = 0; it < 4; ++it) {
            int d0 = (it * NWAVES + w) * 8;
            float v[8];
            #pragma unroll
            for (int jj = 0; jj < 8; ++jj)
                v[jj] = xbl[(long)(d0 + jj) * TT];
            union { short8v s; unsigned short h[8]; } hv;
            #pragma unroll
            for (int jj = 0; jj < 8; ++jj) hv.h[jj] = f2bf(v[jj]);
            int kk = d0 >> 5, lg = (d0 >> 3) & 3;
            int m = lane >> 4, lp = (lane & 15) + lg * 16;
            *(short8v*)(Ahi + (size_t)((m * 16 + kk) * 64 + lp) * 8) = hv.s;
        }
    }
    __syncthreads();

    // ---- GEMM: wave owns 64 codes (4 n-tiles), all 4 m-tiles, K=512 ----
    f32x4 acc[4][4];
    #pragma unroll
    for (int m = 0; m < 4; ++m)
        #pragma unroll
        for (int n = 0; n < 4; ++n)
            acc[m][n] = (f32x4){0.f, 0.f, 0.f, 0.f};

    const short8v* Bhv = (const short8v*)Bph;
    for (int kk = 0; kk < 16; ++kk) {
        short8v bh[4];
        #pragma unroll
        for (int n = 0; n < 4; ++n)
            bh[n] = Bhv[((w * 4 + n) * 16 + kk) * 64 + lane];
        short8v ah[4];
        #pragma unroll
        for (int m = 0; m < 4; ++m)
            ah[m] = *(const short8v*)&Ahi[((size_t)((m * 16 + kk) * 64 + lane)) * 8];
        #pragma unroll
        for (int n = 0; n < 4; ++n)
            #pragma unroll
            for (int m = 0; m < 4; ++m)
                acc[m][n] = __builtin_amdgcn_mfma_f32_16x16x32_bf16(ah[m], bh[n], acc[m][n], 0, 0, 0);
    }

    // ---- per-row wave-min (C/D: col=lane&15, row=(lane>>4)*4+reg) ----
    float sef[4];
    #pragma unroll
    for (int n = 0; n < 4; ++n) sef[n] = se[w * 64 + n * 16 + (lane & 15)];

    #pragma unroll
    for (int m = 0; m < 4; ++m) {
        #pragma unroll
        for (int r4 = 0; r4 < 4; ++r4) {
            float mn = 1e30f;
            #pragma unroll
            for (int n = 0; n < 4; ++n)
                mn = fminf(mn, fmaf(-2.f, acc[m][n][r4], sef[n]));
            #pragma unroll
            for (int off = 1; off < 16; off <<= 1)
                mn = fminf(mn, __shfl_xor(mn, off, 64));
            if ((lane & 15) == 0)
                wrowmin[w * ROWS + m * 16 + (lane >> 4) * 4 + r4] = mn;
        }
    }
    __syncthreads();

    if (tid < ROWS) {
        float g = 1e30f;
        #pragma unroll
        for (int ww = 0; ww < NWAVES; ++ww)
            g = fminf(g, wrowmin[ww * ROWS + tid]);
        gthr[tid] = g + MARGIN;
    }
    __syncthreads();

    // ---- push candidates within margin into per-row slots ----
    #pragma unroll
    for (int m = 0; m < 4; ++m) {
        #pragma unroll
        for (int r4 = 0; r4 < 4; ++r4) {
            int row = m * 16 + (lane >> 4) * 4 + r4;
            float th = gthr[row];
            #pragma unroll
            for (int n = 0; n < 4; ++n) {
                float sc = fmaf(-2.f, acc[m][n][r4], sef[n]);
                if (sc <= th) {
                    int pos = atomicAdd(&rcnt[row], 1);
                    if (pos < CM)
                        rc[row][pos] = (unsigned short)(w * 64 + n * 16 + (lane & 15));
                }
            }
        }
    }
    __syncthreads();

    if (tid < ROWS) {
        unsigned int cnt = (unsigned int)rcnt[tid];
        if (cnt > 0xffffu) cnt = 0xffffu;
        uint4 cw;
        cw.x = cnt | ((unsigned int)rc[tid][6] << 16);
        cw.y = (unsigned int)rc[tid][0] | ((unsigned int)rc[tid][1] << 16);
        cw.z = (unsigned int)rc[tid][2] | ((unsigned int)rc[tid][3] << 16);
        cw.w = (unsigned int)rc[tid][4] | ((unsigned int)rc[tid][5] << 16);
        cands[nbase + tid] = cw;
    }
}

// =============== k2: exact replay + argmin + gather/loss/st ===============
// 256 threads, 16 rows, ~37 KB LDS -> 4 blocks/CU resident
__global__ __launch_bounds__(BT2, 4)
void vq_out(const float* __restrict__ x, const float* __restrict__ E,
            const float* __restrict__ se, const uint4* __restrict__ cands,
            double* __restrict__ loss_acc, float* __restrict__ out) {
    __shared__ __align__(16) float xsf[DD * XLD2];   // 34,816 B
    __shared__ float Pp[4 * ROWS2];
    __shared__ int   prow[PM2];
    __shared__ int   pcand[PM2];
    __shared__ float pdist[PM2];
    __shared__ int   pcnt;
    __shared__ int   fidx[ROWS2];
    __shared__ int   oflag[ROWS2];
    __shared__ float owv[4];
    __shared__ int   owi[4];

    const int tid  = threadIdx.x;
    const int w    = tid >> 6;
    const int lane = tid & 63;
    const int blk  = blockIdx.x;
    const int b    = blk >> 8;                  // 256 blocks per batch
    const int t0   = (blk & 255) * ROWS2;
    const long nbase = (long)b * TT + t0;
    const float* xb = x + (long)b * DD * TT + t0;

    if (tid == 0) pcnt = 0;

    // ---- stage f32 x tile [d][r] (64B per d-row, coalesced) ----
    #pragma unroll
    for (int it = 0; it < 8; ++it) {
        int flat = it * BT2 + tid;              // 2048 float4
        int d  = flat >> 2;
        int r4 = (flat & 3) * 4;
        float4 v = *reinterpret_cast<const float4*>(xb + (long)d * TT + r4);
        *reinterpret_cast<float4*>(&xsf[d * XLD2 + r4]) = v;
    }
    __syncthreads();

    // ---- pw partials (tid<64) || decode candidate lists (tid 64..79) ----
    if (tid < 64) {
        int r = tid & 15, k = tid >> 4;
        Pp[k * ROWS2 + r] = pw128_sq_strided(xsf + r + (k * 128) * XLD2, XLD2);
    } else if (tid < 64 + ROWS2) {
        int r = tid - 64;
        uint4 cw = cands[nbase + r];
        int cnt = (int)(cw.x & 0xffffu);
        oflag[r] = 0;
        if (cnt == 1) {
            fidx[r] = (int)(cw.y & 0xffffu);
        } else if (cnt <= CM) {
            fidx[r] = -1;
            int cs[CM] = {(int)(cw.y & 0xffffu), (int)(cw.y >> 16),
                          (int)(cw.z & 0xffffu), (int)(cw.z >> 16),
                          (int)(cw.w & 0xffffu), (int)(cw.w >> 16),
                          (int)(cw.x >> 16)};
            int base = atomicAdd(&pcnt, cnt);
            for (int i = 0; i < cnt; ++i) {
                prow[base + i]  = r;
                pcand[base + i] = cs[i];
            }
        } else {                                // overflow: full replay
            fidx[r] = -1;
            oflag[r] = 1;
        }
    }
    __syncthreads();

    // ---- exact fp32 replay per candidate pair (numpy semantics) ----
    const int npairs = (pcnt < PM2) ? pcnt : PM2;
    {
        int p = (tid & 63) * 4 + w;             // spread pairs across 4 waves
        if (p < npairs) {
            int r = prow[p], c = pcand[p];
            float sx = __fadd_rn(__fadd_rn(Pp[0 * ROWS2 + r], Pp[1 * ROWS2 + r]),
                                 __fadd_rn(Pp[2 * ROWS2 + r], Pp[3 * ROWS2 + r]));
            const float* Ep = E + (long)c * DD;
            float g = 0.f;
            #pragma unroll 8
            for (int j = 0; j < DD; ++j)
                g = __fmaf_rn(xsf[j * XLD2 + r], Ep[j], g);
            float t1 = __fadd_rn(sx, se[c]);
            pdist[p] = __fsub_rn(t1, __fmul_rn(2.f, g));
        }
    }
    __syncthreads();

    // ---- per-row argmin over pairs (first-occurrence tie-break) ----
    if (tid < ROWS2 && fidx[tid] < 0 && !oflag[tid]) {
        float bd = 1e30f; int bi = KK;
        for (int p = 0; p < npairs; ++p) {
            if (prow[p] != tid) continue;
            float d = pdist[p]; int c = pcand[p];
            if (d < bd || (d == bd && c < bi)) { bd = d; bi = c; }
        }
        fidx[tid] = bi;
    }
    __syncthreads();

    // ---- overflow fallback (rare): full exact replay, 4 codes/thread ----
    for (int r = 0; r < ROWS2; ++r) {
        if (!oflag[r]) continue;                // LDS-uniform branch
        float sx = __fadd_rn(__fadd_rn(Pp[0 * ROWS2 + r], Pp[1 * ROWS2 + r]),
                             __fadd_rn(Pp[2 * ROWS2 + r], Pp[3 * ROWS2 + r]));
        float bd = 1e30f; int bi = KK;
        for (int q = 0; q < 4; ++q) {
            int c = q * BT2 + tid;              // ascending c => ties keep lowest
            const float* Ep = E + (long)c * DD;
            float g = 0.f;
            #pragma unroll 8
            for (int j = 0; j < DD; ++j)
                g = __fmaf_rn(xsf[j * XLD2 + r], Ep[j], g);
            float d = __fsub_rn(__fadd_rn(sx, se[c]), __fmul_rn(2.f, g));
            if (d < bd) { bd = d; bi = c; }
        }
        #pragma unroll
        for (int off = 32; off; off >>= 1) {
            float tv = __shfl_down(bd, off, 64);
            int   ti = __shfl_down(bi, off, 64);
            if (tv < bd || (tv == bd && ti < bi)) { bd = tv; bi = ti; }
        }
        if (lane == 0) { owv[w] = bd; owi[w] = bi; }
        __syncthreads();
        if (tid == 0) {
            float BD = 1e30f; int BI = KK;
            #pragma unroll
            for (int ww = 0; ww < 4; ++ww) {
                if (owv[ww] < BD || (owv[ww] == BD && owi[ww] < BI)) { BD = owv[ww]; BI = owi[ww]; }
            }
            fidx[r] = BI;
        }
        __syncthreads();
    }

    if (tid < ROWS2)
        out[(size_t)NN * DD + 1 + nbase + tid] = (float)fidx[tid];
    __syncthreads();

    // ---- gather rows, quantized_st = fl(x + fl(q-x)), fp64 loss ----
    double lacc = 0.0;
    #pragma unroll
    for (int it = 0; it < 8; ++it) {
        int flat = it * BT2 + tid;              // 2048 float4 = 16 rows * 128
        int r = flat >> 7;
        int j = (flat & 127) * 4;
        int idx = fidx[r];
        float4 ev = *reinterpret_cast<const float4*>(E + (long)idx * DD + j);
        float xv0 = xsf[(j + 0) * XLD2 + r];
        float xv1 = xsf[(j + 1) * XLD2 + r];
        float xv2 = xsf[(j + 2) * XLD2 + r];
        float xv3 = xsf[(j + 3) * XLD2 + r];
        float d0 = __fsub_rn(ev.x, xv0);
        float d1 = __fsub_rn(ev.y, xv1);
        float d2 = __fsub_rn(ev.z, xv2);
        float d3 = __fsub_rn(ev.w, xv3);
        float4 st;
        st.x = __fadd_rn(xv0, d0);
        st.y = __fadd_rn(xv1, d1);
        st.z = __fadd_rn(xv2, d2);
        st.w = __fadd_rn(xv3, d3);
        *reinterpret_cast<float4*>(out + (size_t)(nbase + r) * DD + j) = st;
        lacc += (double)d0 * d0 + (double)d1 * d1 + (double)d2 * d2 + (double)d3 * d3;
    }
    #pragma unroll
    for (int off = 32; off; off >>= 1) lacc += __shfl_down(lacc, off, 64);
    if (lane == 0) atomicAdd(loss_acc, lacc);
}

// ---------------- loss finalize ----------------
__global__ void finalize_kernel(const double* __restrict__ loss_acc, float* __restrict__ out) {
    if (threadIdx.x == 0 && blockIdx.x == 0) {
        out[(size_t)NN * DD] = (float)(1.25 * (*loss_acc) / ((double)NN * DD));
    }
}

extern "C" void kernel_launch(void* const* d_in, const int* in_sizes, int n_in,
                              void* d_out, int out_size, void* d_ws, size_t ws_size,
                              hipStream_t stream) {
    const float* x = (const float*)d_in[0];
    const float* E = (const float*)d_in[1];
    float* out = (float*)d_out;
    double* loss_acc = (double*)d_ws;                                   // 8 B
    float* se = (float*)((char*)d_ws + 64);                             // 4 KB
    unsigned short* Bph = (unsigned short*)((char*)d_ws + 8192);        // 1 MB
    uint4* cands = (uint4*)((char*)d_ws + 8192 + 1048576);              // 1 MB

    hipMemsetAsync(d_ws, 0, 64, stream);
    enorms_exact<<<4, 256, 0, stream>>>(E, se);
    pack_e<<<(KK * DD / 2) / 256, 256, 0, stream>>>(E, Bph);
    vq_filter<<<NN / ROWS, BLOCKT, 0, stream>>>(x, Bph, se, cands);
    vq_out<<<NN / ROWS2, BT2, 0, stream>>>(x, E, se, cands, loss_acc, out);
    finalize_kernel<<<1, 64, 0, stream>>>(loss_acc, out);
}

// Round 8
// 290.721 us; speedup vs baseline: 1.5721x; 1.3505x over previous
//
#include <hip/hip_runtime.h>

#define BB 16
#define DD 512
#define TT 4096
#define KK 1024
#define NN (BB*TT)              // 65536 rows
#define ROWS 64                 // k1: t-rows per block
#define BLOCKT 1024             // k1: 16 waves
#define NWAVES 16
#define MARGIN 1e-3f            // candidate margin (req <=8e-4, 25% slack)
#define CM 6                    // candidate slots per row (6 x 10 bits in u64)
// k2 geometry
#define ROWS2 16
#define BT2 256
#define XLD2 17
#define PM2 128
#define NBLK2 (NN/ROWS2)        // 4096

typedef __attribute__((ext_vector_type(8))) short short8v;   // 8 bf16
typedef __attribute__((ext_vector_type(4))) float f32x4;

// ---- bf16 helper (RNE) ----
__device__ __forceinline__ unsigned short f2bf(float f) {
    unsigned int u = __float_as_uint(f);
    unsigned int r = (u + 0x7fffu + ((u >> 16) & 1u)) >> 16;
    return (unsigned short)r;
}

// ---- numpy pairwise-sum replication (fp32, squares) — verified passing ----
__device__ __forceinline__ float pw128_sq_strided(const float* a, int stride) {
    float V[16];
    #pragma unroll
    for (int l = 0; l < 16; ++l) {
        float q[8];
        #pragma unroll
        for (int k = 0; k < 8; ++k) {
            float e = a[(l + 16 * k) * stride];
            q[k] = __fmul_rn(e, e);
        }
        V[l] = __fadd_rn(__fadd_rn(__fadd_rn(q[0], q[1]), __fadd_rn(q[2], q[3])),
                         __fadd_rn(__fadd_rn(q[4], q[5]), __fadd_rn(q[6], q[7])));
    }
    float u[8];
    #pragma unroll
    for (int l = 0; l < 8; ++l) u[l] = __fadd_rn(V[l], V[l + 8]);
    float v[4];
    #pragma unroll
    for (int l = 0; l < 4; ++l) v[l] = __fadd_rn(u[l], u[l + 4]);
    return __fadd_rn(__fadd_rn(v[0], v[2]), __fadd_rn(v[1], v[3]));
}
__device__ __forceinline__ float pw512_sq_strided(const float* a, int stride) {
    float p0 = pw128_sq_strided(a, stride);
    float p1 = pw128_sq_strided(a + 128 * stride, stride);
    float p2 = pw128_sq_strided(a + 256 * stride, stride);
    float p3 = pw128_sq_strided(a + 384 * stride, stride);
    return __fadd_rn(__fadd_rn(p0, p1), __fadd_rn(p2, p3));
}

// ---------------- exact ||e||^2 per code row ----------------
__global__ void enorms_exact(const float* __restrict__ E, float* __restrict__ se) {
    int i = blockIdx.x * blockDim.x + threadIdx.x;
    if (i < KK) se[i] = pw512_sq_strided(E + (long)i * DD, 1);
}

// ---------------- pack E (hi bf16) into MFMA B-fragment layout (u32 pairs) --
__global__ void pack_e(const float* __restrict__ E, unsigned short* __restrict__ Bph) {
    int i = blockIdx.x * blockDim.x + threadIdx.x;   // 0 .. KK*DD/2-1
    if (i >= KK * DD / 2) return;
    int c = i >> 8;
    int k = (i & 255) * 2;                           // even k; k,k+1 share 8-group
    float2 v = *reinterpret_cast<const float2*>(E + ((long)c << 9) + k);
    int lane = (c & 15) + ((k >> 3) & 3) * 16;
    int hw = (((c >> 4) * 16 + (k >> 5)) * 64 + lane) * 8 + (k & 7);
    unsigned int pk = (unsigned int)f2bf(v.x) | ((unsigned int)f2bf(v.y) << 16);
    *reinterpret_cast<unsigned int*>(Bph + hw) = pk;
}

// =============== k1: MFMA filter -> per-row candidate lists (u64) =========
__global__ __launch_bounds__(BLOCKT)
void vq_filter(const float* __restrict__ x,
               const unsigned short* __restrict__ Bph,
               const float* __restrict__ se,
               unsigned long long* __restrict__ cands) {
    __shared__ __align__(16) unsigned short Ahi[ROWS * DD];  // 64 KB, fragment layout
    __shared__ float wrowmin[NWAVES * ROWS];
    __shared__ float gthr[ROWS];
    __shared__ int   rcnt[ROWS];
    __shared__ unsigned short rc[ROWS][CM];

    const int tid  = threadIdx.x;
    const int w    = tid >> 6;
    const int lane = tid & 63;
    const int blk  = blockIdx.x;
    const int b    = blk >> 6;
    const int t0   = (blk & 63) * ROWS;
    const long nbase = (long)b * TT + t0;
    const float* xb = x + (long)b * DD * TT + t0;

    if (tid < ROWS) {
        rcnt[tid] = 0;
        #pragma unroll
        for (int i = 0; i < CM; ++i) rc[tid][i] = 0;
    }

    // ---- stage x tile -> bf16-hi A fragments (coalesced loads, b128 writes) ----
    {
        const float* xbl = xb + lane;
        #pragma unroll
        for (int it = 0; it < 4; ++it) {
            int d0 = (it * NWAVES + w) * 8;
            float v[8];
            #pragma unroll
            for (int jj = 0; jj < 8; ++jj)
                v[jj] = xbl[(long)(d0 + jj) * TT];
            union { short8v s; unsigned short h[8]; } hv;
            #pragma unroll
            for (int jj = 0; jj < 8; ++jj) hv.h[jj] = f2bf(v[jj]);
            int kk = d0 >> 5, lg = (d0 >> 3) & 3;
            int m = lane >> 4, lp = (lane & 15) + lg * 16;
            *(short8v*)(Ahi + (size_t)((m * 16 + kk) * 64 + lp) * 8) = hv.s;
        }
    }
    __syncthreads();

    // ---- GEMM: wave owns 64 codes (4 n-tiles), all 4 m-tiles, K=512 ----
    f32x4 acc[4][4];
    #pragma unroll
    for (int m = 0; m < 4; ++m)
        #pragma unroll
        for (int n = 0; n < 4; ++n)
            acc[m][n] = (f32x4){0.f, 0.f, 0.f, 0.f};

    const short8v* Bhv = (const short8v*)Bph;
    for (int kk = 0; kk < 16; ++kk) {
        short8v bh[4];
        #pragma unroll
        for (int n = 0; n < 4; ++n)
            bh[n] = Bhv[((w * 4 + n) * 16 + kk) * 64 + lane];
        short8v ah[4];
        #pragma unroll
        for (int m = 0; m < 4; ++m)
            ah[m] = *(const short8v*)&Ahi[((size_t)((m * 16 + kk) * 64 + lane)) * 8];
        #pragma unroll
        for (int n = 0; n < 4; ++n)
            #pragma unroll
            for (int m = 0; m < 4; ++m)
                acc[m][n] = __builtin_amdgcn_mfma_f32_16x16x32_bf16(ah[m], bh[n], acc[m][n], 0, 0, 0);
    }

    // ---- per-row wave-min (C/D: col=lane&15, row=(lane>>4)*4+reg) ----
    float sef[4];
    #pragma unroll
    for (int n = 0; n < 4; ++n) sef[n] = se[w * 64 + n * 16 + (lane & 15)];

    #pragma unroll
    for (int m = 0; m < 4; ++m) {
        #pragma unroll
        for (int r4 = 0; r4 < 4; ++r4) {
            float mn = 1e30f;
            #pragma unroll
            for (int n = 0; n < 4; ++n)
                mn = fminf(mn, fmaf(-2.f, acc[m][n][r4], sef[n]));
            #pragma unroll
            for (int off = 1; off < 16; off <<= 1)
                mn = fminf(mn, __shfl_xor(mn, off, 64));
            if ((lane & 15) == 0)
                wrowmin[w * ROWS + m * 16 + (lane >> 4) * 4 + r4] = mn;
        }
    }
    __syncthreads();

    if (tid < ROWS) {
        float g = 1e30f;
        #pragma unroll
        for (int ww = 0; ww < NWAVES; ++ww)
            g = fminf(g, wrowmin[ww * ROWS + tid]);
        gthr[tid] = g + MARGIN;
    }
    __syncthreads();

    // ---- push candidates within margin into per-row slots ----
    #pragma unroll
    for (int m = 0; m < 4; ++m) {
        #pragma unroll
        for (int r4 = 0; r4 < 4; ++r4) {
            int row = m * 16 + (lane >> 4) * 4 + r4;
            float th = gthr[row];
            #pragma unroll
            for (int n = 0; n < 4; ++n) {
                float sc = fmaf(-2.f, acc[m][n][r4], sef[n]);
                if (sc <= th) {
                    int pos = atomicAdd(&rcnt[row], 1);
                    if (pos < CM)
                        rc[row][pos] = (unsigned short)(w * 64 + n * 16 + (lane & 15));
                }
            }
        }
    }
    __syncthreads();

    if (tid < ROWS) {
        unsigned int cnt = (unsigned int)rcnt[tid];
        if (cnt > 15u) cnt = 15u;
        unsigned long long cw = cnt;
        #pragma unroll
        for (int i = 0; i < CM; ++i)
            cw |= (unsigned long long)(rc[tid][i] & 0x3ffu) << (4 + 10 * i);
        cands[nbase + tid] = cw;
    }
}

// =============== k2: exact replay + argmin + gather/loss/st ===============
// 256 threads, 16 rows, ~37 KB LDS -> 4 blocks/CU; NO global atomics.
__global__ __launch_bounds__(BT2, 4)
void vq_out(const float* __restrict__ x, const float* __restrict__ E,
            const float* __restrict__ se,
            const unsigned long long* __restrict__ cands,
            double* __restrict__ partials, float* __restrict__ out) {
    __shared__ __align__(16) float xsf[DD * XLD2];   // 34,816 B
    __shared__ float Pp[4 * ROWS2];
    __shared__ int   prow[PM2];
    __shared__ int   pcand[PM2];
    __shared__ unsigned long long rmin[ROWS2];
    __shared__ int   pcnt;
    __shared__ int   fidx[ROWS2];
    __shared__ int   oflag[ROWS2];
    __shared__ float owv[4];
    __shared__ int   owi[4];
    __shared__ double wloss[4];

    const int tid  = threadIdx.x;
    const int w    = tid >> 6;
    const int lane = tid & 63;
    const int blk  = blockIdx.x;
    const int b    = blk >> 8;                  // 256 blocks per batch
    const int t0   = (blk & 255) * ROWS2;
    const long nbase = (long)b * TT + t0;
    const float* xb = x + (long)b * DD * TT + t0;

    if (tid == 0) pcnt = 0;
    if (tid < ROWS2) rmin[tid] = ~0ull;

    // ---- stage f32 x tile [d][r] (64B per d-row, coalesced) ----
    #pragma unroll
    for (int it = 0; it < 8; ++it) {
        int flat = it * BT2 + tid;              // 2048 float4
        int d  = flat >> 2;
        int r4 = (flat & 3) * 4;
        float4 v = *reinterpret_cast<const float4*>(xb + (long)d * TT + r4);
        *reinterpret_cast<float4*>(&xsf[d * XLD2 + r4]) = v;
    }
    __syncthreads();

    // ---- pw partials (tid<64) || decode candidate lists (tid 64..79) ----
    if (tid < 64) {
        int r = tid & 15, k = tid >> 4;
        Pp[k * ROWS2 + r] = pw128_sq_strided(xsf + r + (k * 128) * XLD2, XLD2);
    } else if (tid < 64 + ROWS2) {
        int r = tid - 64;
        unsigned long long cw = cands[nbase + r];
        int cnt = (int)(cw & 15u);
        oflag[r] = 0;
        if (cnt == 1) {
            fidx[r] = (int)((cw >> 4) & 0x3ffu);
        } else if (cnt >= 2 && cnt <= CM) {
            fidx[r] = -1;
            int base = atomicAdd(&pcnt, cnt);
            for (int i = 0; i < cnt; ++i) {
                prow[base + i]  = r;
                pcand[base + i] = (int)((cw >> (4 + 10 * i)) & 0x3ffu);
            }
        } else {                                // cnt==0 or overflow: full replay
            fidx[r] = -1;
            oflag[r] = 1;
        }
    }
    __syncthreads();

    // ---- exact fp32 replay per candidate; fused argmin via LDS atomicMin ----
    const int npairs = (pcnt < PM2) ? pcnt : PM2;
    {
        int p = (tid & 63) * 4 + w;             // spread pairs across 4 waves
        if (p < npairs) {
            int r = prow[p], c = pcand[p];
            float sx = __fadd_rn(__fadd_rn(Pp[0 * ROWS2 + r], Pp[1 * ROWS2 + r]),
                                 __fadd_rn(Pp[2 * ROWS2 + r], Pp[3 * ROWS2 + r]));
            const float* Ep = E + (long)c * DD;
            float g = 0.f;
            #pragma unroll 8
            for (int j = 0; j < DD; ++j)
                g = __fmaf_rn(xsf[j * XLD2 + r], Ep[j], g);
            float t1 = __fadd_rn(sx, se[c]);
            float d  = __fsub_rn(t1, __fmul_rn(2.f, g));
            unsigned int bb = __float_as_uint(d);
            unsigned int u  = (bb & 0x80000000u) ? ~bb : (bb | 0x80000000u);
            unsigned long long key = ((unsigned long long)u << 10) | (unsigned int)c;
            atomicMin(&rmin[r], key);           // ties -> lower index (numpy)
        }
    }
    __syncthreads();

    if (tid < ROWS2 && fidx[tid] < 0 && !oflag[tid])
        fidx[tid] = (int)(rmin[tid] & 0x3ffu);
    __syncthreads();

    // ---- overflow fallback (rare): full exact replay, 4 codes/thread ----
    for (int r = 0; r < ROWS2; ++r) {
        if (!oflag[r]) continue;                // LDS-uniform branch
        float sx = __fadd_rn(__fadd_rn(Pp[0 * ROWS2 + r], Pp[1 * ROWS2 + r]),
                             __fadd_rn(Pp[2 * ROWS2 + r], Pp[3 * ROWS2 + r]));
        float bd = 1e30f; int bi = KK;
        for (int q = 0; q < 4; ++q) {
            int c = q * BT2 + tid;              // ascending c => ties keep lowest
            const float* Ep = E + (long)c * DD;
            float g = 0.f;
            #pragma unroll 8
            for (int j = 0; j < DD; ++j)
                g = __fmaf_rn(xsf[j * XLD2 + r], Ep[j], g);
            float d = __fsub_rn(__fadd_rn(sx, se[c]), __fmul_rn(2.f, g));
            if (d < bd) { bd = d; bi = c; }
        }
        #pragma unroll
        for (int off = 32; off; off >>= 1) {
            float tv = __shfl_down(bd, off, 64);
            int   ti = __shfl_down(bi, off, 64);
            if (tv < bd || (tv == bd && ti < bi)) { bd = tv; bi = ti; }
        }
        if (lane == 0) { owv[w] = bd; owi[w] = bi; }
        __syncthreads();
        if (tid == 0) {
            float BD = 1e30f; int BI = KK;
            #pragma unroll
            for (int ww = 0; ww < 4; ++ww) {
                if (owv[ww] < BD || (owv[ww] == BD && owi[ww] < BI)) { BD = owv[ww]; BI = owi[ww]; }
            }
            fidx[r] = BI;
        }
        __syncthreads();
    }

    if (tid < ROWS2)
        out[(size_t)NN * DD + 1 + nbase + tid] = (float)fidx[tid];
    __syncthreads();

    // ---- gather rows, quantized_st = fl(x + fl(q-x)), fp64 loss ----
    double lacc = 0.0;
    #pragma unroll
    for (int it = 0; it < 8; ++it) {
        int flat = it * BT2 + tid;              // 2048 float4 = 16 rows * 128
        int r = flat >> 7;
        int j = (flat & 127) * 4;
        int idx = fidx[r];
        float4 ev = *reinterpret_cast<const float4*>(E + (long)idx * DD + j);
        float xv0 = xsf[(j + 0) * XLD2 + r];
        float xv1 = xsf[(j + 1) * XLD2 + r];
        float xv2 = xsf[(j + 2) * XLD2 + r];
        float xv3 = xsf[(j + 3) * XLD2 + r];
        float d0 = __fsub_rn(ev.x, xv0);
        float d1 = __fsub_rn(ev.y, xv1);
        float d2 = __fsub_rn(ev.z, xv2);
        float d3 = __fsub_rn(ev.w, xv3);
        float4 st;
        st.x = __fadd_rn(xv0, d0);
        st.y = __fadd_rn(xv1, d1);
        st.z = __fadd_rn(xv2, d2);
        st.w = __fadd_rn(xv3, d3);
        *reinterpret_cast<float4*>(out + (size_t)(nbase + r) * DD + j) = st;
        lacc += (double)d0 * d0 + (double)d1 * d1 + (double)d2 * d2 + (double)d3 * d3;
    }
    #pragma unroll
    for (int off = 32; off; off >>= 1) lacc += __shfl_down(lacc, off, 64);
    if (lane == 0) wloss[w] = lacc;
    __syncthreads();
    if (tid == 0)                               // ONE plain store per block
        partials[blk] = wloss[0] + wloss[1] + wloss[2] + wloss[3];
}

// ---------------- loss finalize: sum 4096 block partials ----------------
__global__ void finalize_kernel(const double* __restrict__ partials, float* __restrict__ out) {
    __shared__ double sm[16];
    const int tid = threadIdx.x;                // 1024 threads
    const int w = tid >> 6, lane = tid & 63;
    double a = 0.0;
    #pragma unroll
    for (int i = 0; i < NBLK2 / 1024; ++i)
        a += partials[i * 1024 + tid];
    #pragma unroll
    for (int off = 32; off; off >>= 1) a += __shfl_down(a, off, 64);
    if (lane == 0) sm[w] = a;
    __syncthreads();
    if (tid == 0) {
        double s = 0.0;
        #pragma unroll
        for (int i = 0; i < 16; ++i) s += sm[i];
        out[(size_t)NN * DD] = (float)(1.25 * s / ((double)NN * DD));
    }
}

extern "C" void kernel_launch(void* const* d_in, const int* in_sizes, int n_in,
                              void* d_out, int out_size, void* d_ws, size_t ws_size,
                              hipStream_t stream) {
    const float* x = (const float*)d_in[0];
    const float* E = (const float*)d_in[1];
    float* out = (float*)d_out;
    double* partials = (double*)d_ws;                                       // 32 KB
    float* se = (float*)((char*)d_ws + 32768);                              // 4 KB
    unsigned short* Bph = (unsigned short*)((char*)d_ws + 65536);           // 1 MB
    unsigned long long* cands =
        (unsigned long long*)((char*)d_ws + 65536 + 1048576);               // 512 KB

    enorms_exact<<<4, 256, 0, stream>>>(E, se);
    pack_e<<<(KK * DD / 2) / 256, 256, 0, stream>>>(E, Bph);
    vq_filter<<<NN / ROWS, BLOCKT, 0, stream>>>(x, Bph, se, cands);
    vq_out<<<NBLK2, BT2, 0, stream>>>(x, E, se, cands, partials, out);
    finalize_kernel<<<1, 1024, 0, stream>>>(partials, out);
}

// Round 9
// 261.152 us; speedup vs baseline: 1.7501x; 1.1132x over previous
//
#include <hip/hip_runtime.h>

#define BB 16
#define DD 512
#define TT 4096
#define KK 1024
#define NN (BB*TT)              // 65536 rows
#define ROWS 64                 // k1: t-rows per block
#define BLOCKT 1024             // k1: 16 waves
#define NWAVES 16
#define MARGIN 1e-3f            // candidate margin (req <=8e-4, 25% slack)
#define CM 6                    // candidate slots per row (6 x 10 bits in u64)
// k2 geometry
#define ROWS2 16
#define BT2 256
#define XLD2 516                // floats per x row: 2064 B, 16B-aligned, bank-skewed
#define PM2 128
#define NBLK2 (NN/ROWS2)        // 4096

typedef __attribute__((ext_vector_type(8))) short short8v;   // 8 bf16
typedef __attribute__((ext_vector_type(4))) float f32x4;

// ---- bf16 helper (RNE) ----
__device__ __forceinline__ unsigned short f2bf(float f) {
    unsigned int u = __float_as_uint(f);
    unsigned int r = (u + 0x7fffu + ((u >> 16) & 1u)) >> 16;
    return (unsigned short)r;
}

// ---- numpy pairwise-sum replication (fp32, squares) — verified passing ----
__device__ __forceinline__ float pw128_sq_strided(const float* a, int stride) {
    float V[16];
    #pragma unroll
    for (int l = 0; l < 16; ++l) {
        float q[8];
        #pragma unroll
        for (int k = 0; k < 8; ++k) {
            float e = a[(l + 16 * k) * stride];
            q[k] = __fmul_rn(e, e);
        }
        V[l] = __fadd_rn(__fadd_rn(__fadd_rn(q[0], q[1]), __fadd_rn(q[2], q[3])),
                         __fadd_rn(__fadd_rn(q[4], q[5]), __fadd_rn(q[6], q[7])));
    }
    float u[8];
    #pragma unroll
    for (int l = 0; l < 8; ++l) u[l] = __fadd_rn(V[l], V[l + 8]);
    float v[4];
    #pragma unroll
    for (int l = 0; l < 4; ++l) v[l] = __fadd_rn(u[l], u[l + 4]);
    return __fadd_rn(__fadd_rn(v[0], v[2]), __fadd_rn(v[1], v[3]));
}
__device__ __forceinline__ float pw512_sq_strided(const float* a, int stride) {
    float p0 = pw128_sq_strided(a, stride);
    float p1 = pw128_sq_strided(a + 128 * stride, stride);
    float p2 = pw128_sq_strided(a + 256 * stride, stride);
    float p3 = pw128_sq_strided(a + 384 * stride, stride);
    return __fadd_rn(__fadd_rn(p0, p1), __fadd_rn(p2, p3));
}

// ---------------- exact ||e||^2 per code row ----------------
__global__ void enorms_exact(const float* __restrict__ E, float* __restrict__ se) {
    int i = blockIdx.x * blockDim.x + threadIdx.x;
    if (i < KK) se[i] = pw512_sq_strided(E + (long)i * DD, 1);
}

// ---------------- pack E (hi bf16) into MFMA B-fragment layout (u32 pairs) --
__global__ void pack_e(const float* __restrict__ E, unsigned short* __restrict__ Bph) {
    int i = blockIdx.x * blockDim.x + threadIdx.x;   // 0 .. KK*DD/2-1
    if (i >= KK * DD / 2) return;
    int c = i >> 8;
    int k = (i & 255) * 2;                           // even k; k,k+1 share 8-group
    float2 v = *reinterpret_cast<const float2*>(E + ((long)c << 9) + k);
    int lane = (c & 15) + ((k >> 3) & 3) * 16;
    int hw = (((c >> 4) * 16 + (k >> 5)) * 64 + lane) * 8 + (k & 7);
    unsigned int pk = (unsigned int)f2bf(v.x) | ((unsigned int)f2bf(v.y) << 16);
    *reinterpret_cast<unsigned int*>(Bph + hw) = pk;
}

// =============== k1: MFMA filter -> per-row candidate lists (u64) =========
__global__ __launch_bounds__(BLOCKT)
void vq_filter(const float* __restrict__ x,
               const unsigned short* __restrict__ Bph,
               const float* __restrict__ se,
               unsigned long long* __restrict__ cands) {
    __shared__ __align__(16) unsigned short Ahi[ROWS * DD];  // 64 KB, fragment layout
    __shared__ float wrowmin[NWAVES * ROWS];
    __shared__ float gthr[ROWS];
    __shared__ int   rcnt[ROWS];
    __shared__ unsigned short rc[ROWS][CM];

    const int tid  = threadIdx.x;
    const int w    = tid >> 6;
    const int lane = tid & 63;
    const int blk  = blockIdx.x;
    const int b    = blk >> 6;
    const int t0   = (blk & 63) * ROWS;
    const long nbase = (long)b * TT + t0;
    const float* xb = x + (long)b * DD * TT + t0;

    if (tid < ROWS) {
        rcnt[tid] = 0;
        #pragma unroll
        for (int i = 0; i < CM; ++i) rc[tid][i] = 0;
    }

    // ---- stage x tile -> bf16-hi A fragments (coalesced loads, b128 writes) ----
    {
        const float* xbl = xb + lane;
        #pragma unroll
        for (int it = 0; it < 4; ++it) {
            int d0 = (it * NWAVES + w) * 8;
            float v[8];
            #pragma unroll
            for (int jj = 0; jj < 8; ++jj)
                v[jj] = xbl[(long)(d0 + jj) * TT];
            union { short8v s; unsigned short h[8]; } hv;
            #pragma unroll
            for (int jj = 0; jj < 8; ++jj) hv.h[jj] = f2bf(v[jj]);
            int kk = d0 >> 5, lg = (d0 >> 3) & 3;
            int m = lane >> 4, lp = (lane & 15) + lg * 16;
            *(short8v*)(Ahi + (size_t)((m * 16 + kk) * 64 + lp) * 8) = hv.s;
        }
    }
    __syncthreads();

    // ---- GEMM: wave owns 64 codes, K=512; B software-prefetch pipeline ----
    f32x4 acc[4][4];
    #pragma unroll
    for (int m = 0; m < 4; ++m)
        #pragma unroll
        for (int n = 0; n < 4; ++n)
            acc[m][n] = (f32x4){0.f, 0.f, 0.f, 0.f};

    const short8v* Bhv = (const short8v*)Bph;
    short8v bh[4];
    #pragma unroll
    for (int n = 0; n < 4; ++n)
        bh[n] = Bhv[((w * 4 + n) * 16 + 0) * 64 + lane];

    for (int kk = 0; kk < 16; ++kk) {
        short8v bhn[4];
        if (kk < 15) {
            #pragma unroll
            for (int n = 0; n < 4; ++n)
                bhn[n] = Bhv[((w * 4 + n) * 16 + kk + 1) * 64 + lane];
        }
        short8v ah[4];
        #pragma unroll
        for (int m = 0; m < 4; ++m)
            ah[m] = *(const short8v*)&Ahi[((size_t)((m * 16 + kk) * 64 + lane)) * 8];
        #pragma unroll
        for (int n = 0; n < 4; ++n)
            #pragma unroll
            for (int m = 0; m < 4; ++m)
                acc[m][n] = __builtin_amdgcn_mfma_f32_16x16x32_bf16(ah[m], bh[n], acc[m][n], 0, 0, 0);
        if (kk < 15) {
            #pragma unroll
            for (int n = 0; n < 4; ++n) bh[n] = bhn[n];
        }
    }

    // ---- per-row wave-min (C/D: col=lane&15, row=(lane>>4)*4+reg) ----
    float sef[4];
    #pragma unroll
    for (int n = 0; n < 4; ++n) sef[n] = se[w * 64 + n * 16 + (lane & 15)];

    #pragma unroll
    for (int m = 0; m < 4; ++m) {
        #pragma unroll
        for (int r4 = 0; r4 < 4; ++r4) {
            float mn = 1e30f;
            #pragma unroll
            for (int n = 0; n < 4; ++n)
                mn = fminf(mn, fmaf(-2.f, acc[m][n][r4], sef[n]));
            #pragma unroll
            for (int off = 1; off < 16; off <<= 1)
                mn = fminf(mn, __shfl_xor(mn, off, 64));
            if ((lane & 15) == 0)
                wrowmin[w * ROWS + m * 16 + (lane >> 4) * 4 + r4] = mn;
        }
    }
    __syncthreads();

    if (tid < ROWS) {
        float g = 1e30f;
        #pragma unroll
        for (int ww = 0; ww < NWAVES; ++ww)
            g = fminf(g, wrowmin[ww * ROWS + tid]);
        gthr[tid] = g + MARGIN;
    }
    __syncthreads();

    // ---- push candidates within margin into per-row slots ----
    #pragma unroll
    for (int m = 0; m < 4; ++m) {
        #pragma unroll
        for (int r4 = 0; r4 < 4; ++r4) {
            int row = m * 16 + (lane >> 4) * 4 + r4;
            float th = gthr[row];
            #pragma unroll
            for (int n = 0; n < 4; ++n) {
                float sc = fmaf(-2.f, acc[m][n][r4], sef[n]);
                if (sc <= th) {
                    int pos = atomicAdd(&rcnt[row], 1);
                    if (pos < CM)
                        rc[row][pos] = (unsigned short)(w * 64 + n * 16 + (lane & 15));
                }
            }
        }
    }
    __syncthreads();

    if (tid < ROWS) {
        unsigned int cnt = (unsigned int)rcnt[tid];
        if (cnt > 15u) cnt = 15u;
        unsigned long long cw = cnt;
        #pragma unroll
        for (int i = 0; i < CM; ++i)
            cw |= (unsigned long long)(rc[tid][i] & 0x3ffu) << (4 + 10 * i);
        cands[nbase + tid] = cw;
    }
}

// =============== k2: exact replay + argmin + gather/loss/st ===============
// 256 threads, 16 rows, row-major f32 x tile; common case = 2 barriers.
__global__ __launch_bounds__(BT2, 4)
void vq_out(const float* __restrict__ x, const float* __restrict__ E,
            const float* __restrict__ se,
            const unsigned long long* __restrict__ cands,
            double* __restrict__ partials, float* __restrict__ out) {
    __shared__ __align__(16) float xsf[ROWS2 * XLD2];   // 33,024 B, row-major [r][d]
    __shared__ float Pp[4 * ROWS2];
    __shared__ int   prow[PM2];
    __shared__ int   pcand[PM2];
    __shared__ unsigned long long rmin[ROWS2];
    __shared__ int   pcnt, oany;
    __shared__ int   fidx[ROWS2];
    __shared__ int   oflag[ROWS2];
    __shared__ float owv[4];
    __shared__ int   owi[4];
    __shared__ double wloss[4];

    const int tid  = threadIdx.x;
    const int w    = tid >> 6;
    const int lane = tid & 63;
    const int blk  = blockIdx.x;
    const int b    = blk >> 8;                  // 256 blocks per batch
    const int t0   = (blk & 255) * ROWS2;
    const long nbase = (long)b * TT + t0;
    const float* xb = x + (long)b * DD * TT + t0;

    // ---- init + decode (all in wave 0, in-order within wave) ----
    if (tid == 0) { pcnt = 0; oany = 0; }
    if (tid < ROWS2) {
        rmin[tid] = ~0ull;
        int r = tid;
        unsigned long long cw = cands[nbase + r];
        int cnt = (int)(cw & 15u);
        oflag[r] = 0;
        if (cnt == 1) {
            fidx[r] = (int)((cw >> 4) & 0x3ffu);
        } else if (cnt >= 2 && cnt <= CM) {
            fidx[r] = -1;
            int base = atomicAdd(&pcnt, cnt);
            for (int i = 0; i < cnt; ++i) {
                prow[base + i]  = r;
                pcand[base + i] = (int)((cw >> (4 + 10 * i)) & 0x3ffu);
            }
        } else {                                // cnt==0 or overflow: full replay
            fidx[r] = -1;
            oflag[r] = 1;
            atomicOr(&oany, 1);
        }
    }

    // ---- stage f32 x tile ROW-major [r][d] (coalesced 64B global reads) ----
    #pragma unroll
    for (int it = 0; it < 8; ++it) {
        int flat = it * BT2 + tid;              // 2048 float4
        int d  = flat >> 2;
        int r4 = (flat & 3) * 4;
        float4 v = *reinterpret_cast<const float4*>(xb + (long)d * TT + r4);
        xsf[(r4 + 0) * XLD2 + d] = v.x;         // 2-way bank alias = free
        xsf[(r4 + 1) * XLD2 + d] = v.y;
        xsf[(r4 + 2) * XLD2 + d] = v.z;
        xsf[(r4 + 3) * XLD2 + d] = v.w;
    }
    __syncthreads();

    const int npairs = (pcnt < PM2) ? pcnt : PM2;
    if (npairs > 0 || oany) {
        // ---- exact pairwise partials (contiguous row reads) ----
        if (tid < 64) {
            int r = tid & 15, k = tid >> 4;
            Pp[k * ROWS2 + r] = pw128_sq_strided(xsf + r * XLD2 + k * 128, 1);
        }
        __syncthreads();

        // ---- exact fp32 replay; float4 loads, sequential scalar chain ----
        {
            int p = (tid & 63) * 4 + w;
            if (p < npairs) {
                int r = prow[p], c = pcand[p];
                float sx = __fadd_rn(__fadd_rn(Pp[0 * ROWS2 + r], Pp[1 * ROWS2 + r]),
                                     __fadd_rn(Pp[2 * ROWS2 + r], Pp[3 * ROWS2 + r]));
                const float4* Ep4 = reinterpret_cast<const float4*>(E + (long)c * DD);
                const float4* Xp4 = reinterpret_cast<const float4*>(xsf + r * XLD2);
                float g = 0.f;
                #pragma unroll 4
                for (int jj = 0; jj < 128; ++jj) {
                    float4 e4 = Ep4[jj];
                    float4 x4 = Xp4[jj];
                    g = __fmaf_rn(x4.x, e4.x, g);   // exact numpy order
                    g = __fmaf_rn(x4.y, e4.y, g);
                    g = __fmaf_rn(x4.z, e4.z, g);
                    g = __fmaf_rn(x4.w, e4.w, g);
                }
                float t1 = __fadd_rn(sx, se[c]);
                float d  = __fsub_rn(t1, __fmul_rn(2.f, g));
                unsigned int bb = __float_as_uint(d);
                unsigned int u  = (bb & 0x80000000u) ? ~bb : (bb | 0x80000000u);
                unsigned long long key = ((unsigned long long)u << 10) | (unsigned int)c;
                atomicMin(&rmin[r], key);       // ties -> lower index (numpy)
            }
        }
        __syncthreads();

        if (tid < ROWS2 && fidx[tid] < 0 && !oflag[tid])
            fidx[tid] = (int)(rmin[tid] & 0x3ffu);

        // ---- overflow fallback (rare): full exact replay, 4 codes/thread ----
        if (oany) {
            for (int r = 0; r < ROWS2; ++r) {
                if (!oflag[r]) continue;        // LDS-uniform branch
                float sx = __fadd_rn(__fadd_rn(Pp[0 * ROWS2 + r], Pp[1 * ROWS2 + r]),
                                     __fadd_rn(Pp[2 * ROWS2 + r], Pp[3 * ROWS2 + r]));
                const float4* Xp4 = reinterpret_cast<const float4*>(xsf + r * XLD2);
                float bd = 1e30f; int bi = KK;
                for (int q = 0; q < 4; ++q) {
                    int c = q * BT2 + tid;      // ascending c => ties keep lowest
                    const float4* Ep4 = reinterpret_cast<const float4*>(E + (long)c * DD);
                    float g = 0.f;
                    #pragma unroll 4
                    for (int jj = 0; jj < 128; ++jj) {
                        float4 e4 = Ep4[jj];
                        float4 x4 = Xp4[jj];
                        g = __fmaf_rn(x4.x, e4.x, g);
                        g = __fmaf_rn(x4.y, e4.y, g);
                        g = __fmaf_rn(x4.z, e4.z, g);
                        g = __fmaf_rn(x4.w, e4.w, g);
                    }
                    float d = __fsub_rn(__fadd_rn(sx, se[c]), __fmul_rn(2.f, g));
                    if (d < bd) { bd = d; bi = c; }
                }
                #pragma unroll
                for (int off = 32; off; off >>= 1) {
                    float tv = __shfl_down(bd, off, 64);
                    int   ti = __shfl_down(bi, off, 64);
                    if (tv < bd || (tv == bd && ti < bi)) { bd = tv; bi = ti; }
                }
                if (lane == 0) { owv[w] = bd; owi[w] = bi; }
                __syncthreads();
                if (tid == 0) {
                    float BD = 1e30f; int BI = KK;
                    #pragma unroll
                    for (int ww = 0; ww < 4; ++ww) {
                        if (owv[ww] < BD || (owv[ww] == BD && owi[ww] < BI)) { BD = owv[ww]; BI = owi[ww]; }
                    }
                    fidx[r] = BI;
                }
                __syncthreads();
            }
        }
        __syncthreads();                        // fidx final
    }

    if (tid < ROWS2)
        out[(size_t)NN * DD + 1 + nbase + tid] = (float)fidx[tid];

    // ---- gather rows, quantized_st = fl(x + fl(q-x)), fp64 loss ----
    double lacc = 0.0;
    #pragma unroll
    for (int it = 0; it < 8; ++it) {
        int flat = it * BT2 + tid;              // 2048 float4 = 16 rows * 128
        int r = flat >> 7;
        int j = (flat & 127) * 4;
        int idx = fidx[r];
        float4 ev = *reinterpret_cast<const float4*>(E + (long)idx * DD + j);
        float4 xv = *reinterpret_cast<const float4*>(&xsf[r * XLD2 + j]);  // conflict-free b128
        float d0 = __fsub_rn(ev.x, xv.x);
        float d1 = __fsub_rn(ev.y, xv.y);
        float d2 = __fsub_rn(ev.z, xv.z);
        float d3 = __fsub_rn(ev.w, xv.w);
        float4 st;
        st.x = __fadd_rn(xv.x, d0);
        st.y = __fadd_rn(xv.y, d1);
        st.z = __fadd_rn(xv.z, d2);
        st.w = __fadd_rn(xv.w, d3);
        *reinterpret_cast<float4*>(out + (size_t)(nbase + r) * DD + j) = st;
        lacc += (double)d0 * d0 + (double)d1 * d1 + (double)d2 * d2 + (double)d3 * d3;
    }
    #pragma unroll
    for (int off = 32; off; off >>= 1) lacc += __shfl_down(lacc, off, 64);
    if (lane == 0) wloss[w] = lacc;
    __syncthreads();
    if (tid == 0)                               // ONE plain store per block
        partials[blk] = wloss[0] + wloss[1] + wloss[2] + wloss[3];
}

// ---------------- loss finalize: sum 4096 block partials ----------------
__global__ void finalize_kernel(const double* __restrict__ partials, float* __restrict__ out) {
    __shared__ double sm[16];
    const int tid = threadIdx.x;                // 1024 threads
    const int w = tid >> 6, lane = tid & 63;
    double a = 0.0;
    #pragma unroll
    for (int i = 0; i < NBLK2 / 1024; ++i)
        a += partials[i * 1024 + tid];
    #pragma unroll
    for (int off = 32; off; off >>= 1) a += __shfl_down(a, off, 64);
    if (lane == 0) sm[w] = a;
    __syncthreads();
    if (tid == 0) {
        double s = 0.0;
        #pragma unroll
        for (int i = 0; i < 16; ++i) s += sm[i];
        out[(size_t)NN * DD] = (float)(1.25 * s / ((double)NN * DD));
    }
}

extern "C" void kernel_launch(void* const* d_in, const int* in_sizes, int n_in,
                              void* d_out, int out_size, void* d_ws, size_t ws_size,
                              hipStream_t stream) {
    const float* x = (const float*)d_in[0];
    const float* E = (const float*)d_in[1];
    float* out = (float*)d_out;
    double* partials = (double*)d_ws;                                       // 32 KB
    float* se = (float*)((char*)d_ws + 32768);                              // 4 KB
    unsigned short* Bph = (unsigned short*)((char*)d_ws + 65536);           // 1 MB
    unsigned long long* cands =
        (unsigned long long*)((char*)d_ws + 65536 + 1048576);               // 512 KB

    enorms_exact<<<4, 256, 0, stream>>>(E, se);
    pack_e<<<(KK * DD / 2) / 256, 256, 0, stream>>>(E, Bph);
    vq_filter<<<NN / ROWS, BLOCKT, 0, stream>>>(x, Bph, se, cands);
    vq_out<<<NBLK2, BT2, 0, stream>>>(x, E, se, cands, partials, out);
    finalize_kernel<<<1, 1024, 0, stream>>>(partials, out);
}